// Round 5
// baseline (85056.744 us; speedup 1.0000x reference)
//
#include <hip/hip_runtime.h>

// Problem constants (B,T,S,L,D_IN,OUT,W = 256,512,256,36,8,10,256)
#define Tt   512
#define Ll   36
#define DIN  8
#define OUTd 10
// scan decomposition: 8 groups x 32 blocks; block = (group batch rows 32) x (n-slice 288 = 8 s)
#define GB   32

typedef __attribute__((ext_vector_type(8))) short short8;
typedef __attribute__((ext_vector_type(4))) float f32x4;

__device__ __forceinline__ unsigned short f2bf(float f) {
    union { float f; unsigned int u; } v; v.f = f;
    unsigned int r = v.u + 0x7fffu + ((v.u >> 16) & 1u);   // RNE
    return (unsigned short)(r >> 16);
}
__device__ __forceinline__ float bf2f(unsigned short u) {
    union { unsigned int u; float f; } v; v.u = ((unsigned int)u) << 16;
    return v.f;
}
__device__ __forceinline__ float sp_f(float x) {      // jax.nn.softplus
    return fmaxf(x, 0.f) + __logf(1.f + __expf(-fabsf(x)));
}
__device__ __forceinline__ float tanh_f(float x) {
    float e = __expf(2.f * x);
    return 1.f - 2.f / (e + 1.f);
}

// ---- agent-scope (sc1 / LLC-coherent) helpers for cross-block data (h, barrier) ----
__device__ __forceinline__ unsigned long long ldg64(const void* p) {
    return __hip_atomic_load((const unsigned long long*)p, __ATOMIC_RELAXED, __HIP_MEMORY_SCOPE_AGENT);
}
__device__ __forceinline__ float ldgf(const float* p) {
    return __hip_atomic_load(p, __ATOMIC_RELAXED, __HIP_MEMORY_SCOPE_AGENT);
}
__device__ __forceinline__ void stg64(void* p, unsigned long long v) {
    __hip_atomic_store((unsigned long long*)p, v, __ATOMIC_RELAXED, __HIP_MEMORY_SCOPE_AGENT);
}
union U64F2 { unsigned long long u; float f[2]; unsigned short s[4]; };

__device__ __forceinline__ void cast_quad(const float* src, unsigned short* dh,
                                          unsigned short* dl, long u) {
    f32x4 f = *(const f32x4*)(src + u * 4);
    U64F2 H, L;
#pragma unroll
    for (int q = 0; q < 4; ++q) {
        float v = f[q];
        unsigned short hi = f2bf(v);
        H.s[q] = hi;
        L.s[q] = f2bf(v - bf2f(hi));
    }
    *(unsigned long long*)(dh + u * 4) = H.u;
    *(unsigned long long*)(dl + u * 4) = L.u;
}

// ================= prep: init MLP (blk<8), W1/W2 cast (8..15), W3 cast (16..255) ==========
__global__ __launch_bounds__(256) void prep_kernel(
    const float* __restrict__ x0,
    const float* __restrict__ iW1, const float* __restrict__ ib1,
    const float* __restrict__ iW2, const float* __restrict__ ib2,
    const float* __restrict__ iW3, const float* __restrict__ ib3,
    const float* __restrict__ vW1, const float* __restrict__ vW2,
    const float* __restrict__ vW3,
    float* __restrict__ h,
    unsigned short* __restrict__ w1h, unsigned short* __restrict__ w1l,
    unsigned short* __restrict__ w2h, unsigned short* __restrict__ w2l,
    unsigned short* __restrict__ w3h, unsigned short* __restrict__ w3l) {
    const int tid = threadIdx.x, blk = blockIdx.x;
    if (blk < 8) {
        __shared__ float x0s[32][DIN];
        __shared__ float h1[32 * 257];
        __shared__ float h2[32 * 257];
        const int b0 = blk * 32;
        x0s[tid >> 3][tid & 7] = x0[(b0 + (tid >> 3)) * DIN + (tid & 7)];
        __syncthreads();
        const int j = tid;
        {
            float w[DIN];
#pragma unroll
            for (int k = 0; k < DIN; ++k) w[k] = iW1[j * DIN + k];
            float bias = ib1[j];
            for (int r = 0; r < 32; ++r) {
                float acc = bias;
#pragma unroll
                for (int k = 0; k < DIN; ++k) acc += x0s[r][k] * w[k];
                h1[r * 257 + j] = sp_f(acc);
            }
        }
        __syncthreads();
        {
            float bias = ib2[j];
            for (int rb = 0; rb < 4; ++rb) {
                float a8[8];
#pragma unroll
                for (int rr = 0; rr < 8; ++rr) a8[rr] = bias;
                for (int k = 0; k < 256; ++k) {
                    float wv = iW2[j * 256 + k];
#pragma unroll
                    for (int rr = 0; rr < 8; ++rr) a8[rr] += h1[(rb * 8 + rr) * 257 + k] * wv;
                }
#pragma unroll
                for (int rr = 0; rr < 8; ++rr) h2[(rb * 8 + rr) * 257 + j] = sp_f(a8[rr]);
            }
        }
        __syncthreads();
        {
            float bias = ib3[j];
            for (int rb = 0; rb < 4; ++rb) {
                float a8[8];
#pragma unroll
                for (int rr = 0; rr < 8; ++rr) a8[rr] = bias;
                for (int k = 0; k < 256; ++k) {
                    float wv = iW3[j * 256 + k];
#pragma unroll
                    for (int rr = 0; rr < 8; ++rr) a8[rr] += h2[(rb * 8 + rr) * 257 + k] * wv;
                }
#pragma unroll
                for (int rr = 0; rr < 8; ++rr)
                    h[(b0 + rb * 8 + rr) * 256 + j] = a8[rr];
            }
        }
    } else if (blk < 16) {
        const int idx = blk - 8;
        const float* src = (idx < 4) ? vW1 : vW2;
        unsigned short* dh = (idx < 4) ? w1h : w2h;
        unsigned short* dl = (idx < 4) ? w1l : w2l;
        const int part = idx & 3;
        for (int u = part * 4096 + tid; u < (part + 1) * 4096; u += 256)
            cast_quad(src, dh, dl, u);
    } else {
        for (long u = (long)(blk - 16) * 256 + tid; u < 589824; u += 240L * 256)
            cast_quad(vW3, w3h, w3l, u);
    }
}

// ================= scan: 256 blocks = 8 groups x 32; one group barrier per step =========
__global__ __launch_bounds__(256, 1) void scan_kernel(
    const float* __restrict__ logsigs,
    const float* __restrict__ vb1, const float* __restrict__ vb2,
    const float* __restrict__ vb3,
    const float* __restrict__ roW, const float* __restrict__ rob,
    const unsigned short* __restrict__ w1h, const unsigned short* __restrict__ w1l,
    const unsigned short* __restrict__ w2h, const unsigned short* __restrict__ w2l,
    const unsigned short* __restrict__ w3h, const unsigned short* __restrict__ w3l,
    float* __restrict__ out, float* h, int* bar) {
    __shared__ short hlh[32 * 264], hll[32 * 264];
    __shared__ short z1h[32 * 264], z1l[32 * 264];
    __shared__ short z2h[32 * 264], z2l[32 * 264];
    __shared__ float ml[32 * 296];
    __shared__ float lss[32 * 40];
    __shared__ float hloc[256];       // this block's exclusive h slice: 32 rows x 8 s
    __shared__ float hrow[256];       // fp32 h of this block's readout row

    const int tid = threadIdx.x, blk = blockIdx.x;
    const int lane = tid & 63, wv = tid >> 6, quad = lane >> 4, l15 = lane & 15;
    const int g = blk >> 5, j = blk & 31;
    const int b0 = g * 32;            // group batch base
    const int n0 = j * 288;           // W3 n-slice base
    const int s0 = j * 8;             // owned s-slice base
    const int rowR = b0 + j;          // readout row owned by this block
    const f32x4 zero4 = {0.f, 0.f, 0.f, 0.f};
    int* garr = bar + g * 64;         // group arrive counter
    int* grel = bar + g * 64 + 32;    // group release word

    // initial exclusive h slice from h0 (written by prep kernel)
    {
        int row = tid >> 3, sr = tid & 7;
        hloc[tid] = ldgf(h + (b0 + row) * 256 + s0 + sr);
    }

    for (int t = 0; t < Tt; ++t) {
        // ---- gather h (sc1, LLC) + hi/lo split; stage hrow; stage lss ----
        for (int i = tid; i < 4096; i += 256) {
            int r = i >> 7, c = (i & 127) * 2;
            U64F2 v; v.u = ldg64(h + (b0 + r) * 256 + c);
#pragma unroll
            for (int q = 0; q < 2; ++q) {
                float f = v.f[q];
                unsigned short hi = f2bf(f);
                hlh[r * 264 + c + q] = (short)hi;
                hll[r * 264 + c + q] = (short)f2bf(f - bf2f(hi));
            }
        }
        if (tid < 128) {
            U64F2 v; v.u = ldg64(h + (long)rowR * 256 + tid * 2);
            hrow[tid * 2] = v.f[0]; hrow[tid * 2 + 1] = v.f[1];
        }
        for (int i = tid; i < 32 * Ll; i += 256) {
            int r = i / Ll, l = i - r * Ll;
            lss[r * 40 + l] = logsigs[((long)(b0 + r) * Tt + t) * Ll + l];
        }
        __syncthreads();

        // ---- readout out[rowR, t, :] (exact fp32) ----
        if (tid < OUTd) {
            float acc = rob[tid];
            const float* wp = roW + tid * 256;
            for (int s = 0; s < 256; s += 4) {
                f32x4 hv = *(const f32x4*)(const void*)&hrow[s];
                f32x4 w4 = *(const f32x4*)(wp + s);
                acc += hv[0] * w4[0] + hv[1] * w4[1] + hv[2] * w4[2] + hv[3] * w4[3];
            }
            out[((long)rowR * 513 + t) * OUTd + tid] = acc;
        }

        // ---- z1 = sp(h W1^T)  (redundant per block, 32 rows) ----
        {
            const int mt = wv >> 1, nb = (wv & 1) * 8;
            f32x4 acc[8] = {zero4, zero4, zero4, zero4, zero4, zero4, zero4, zero4};
            for (int k0 = 0; k0 < 256; k0 += 32) {
                short8 ah = *(const short8*)(const void*)&hlh[(mt * 16 + l15) * 264 + k0 + quad * 8];
                short8 al = *(const short8*)(const void*)&hll[(mt * 16 + l15) * 264 + k0 + quad * 8];
#pragma unroll
                for (int i = 0; i < 8; ++i) {
                    int n = (nb + i) * 16 + l15;
                    short8 bh = *(const short8*)(const void*)(w1h + n * 256 + k0 + quad * 8);
                    short8 bl = *(const short8*)(const void*)(w1l + n * 256 + k0 + quad * 8);
                    acc[i] = __builtin_amdgcn_mfma_f32_16x16x32_bf16(ah, bh, acc[i], 0, 0, 0);
                    acc[i] = __builtin_amdgcn_mfma_f32_16x16x32_bf16(ah, bl, acc[i], 0, 0, 0);
                    acc[i] = __builtin_amdgcn_mfma_f32_16x16x32_bf16(al, bh, acc[i], 0, 0, 0);
                }
            }
#pragma unroll
            for (int i = 0; i < 8; ++i) {
                int n = (nb + i) * 16 + l15;
                float bias = vb1[n];
#pragma unroll
                for (int r = 0; r < 4; ++r) {
                    int row = mt * 16 + quad * 4 + r;
                    float v = sp_f(acc[i][r] + bias);
                    unsigned short hi = f2bf(v);
                    z1h[row * 264 + n] = (short)hi;
                    z1l[row * 264 + n] = (short)f2bf(v - bf2f(hi));
                }
            }
        }
        __syncthreads();

        // ---- z2 = sp(z1 W2^T) ----
        {
            const int mt = wv >> 1, nb = (wv & 1) * 8;
            f32x4 acc[8] = {zero4, zero4, zero4, zero4, zero4, zero4, zero4, zero4};
            for (int k0 = 0; k0 < 256; k0 += 32) {
                short8 ah = *(const short8*)(const void*)&z1h[(mt * 16 + l15) * 264 + k0 + quad * 8];
                short8 al = *(const short8*)(const void*)&z1l[(mt * 16 + l15) * 264 + k0 + quad * 8];
#pragma unroll
                for (int i = 0; i < 8; ++i) {
                    int n = (nb + i) * 16 + l15;
                    short8 bh = *(const short8*)(const void*)(w2h + n * 256 + k0 + quad * 8);
                    short8 bl = *(const short8*)(const void*)(w2l + n * 256 + k0 + quad * 8);
                    acc[i] = __builtin_amdgcn_mfma_f32_16x16x32_bf16(ah, bh, acc[i], 0, 0, 0);
                    acc[i] = __builtin_amdgcn_mfma_f32_16x16x32_bf16(ah, bl, acc[i], 0, 0, 0);
                    acc[i] = __builtin_amdgcn_mfma_f32_16x16x32_bf16(al, bh, acc[i], 0, 0, 0);
                }
            }
#pragma unroll
            for (int i = 0; i < 8; ++i) {
                int n = (nb + i) * 16 + l15;
                float bias = vb2[n];
#pragma unroll
                for (int r = 0; r < 4; ++r) {
                    int row = mt * 16 + quad * 4 + r;
                    float v = sp_f(acc[i][r] + bias);
                    unsigned short hi = f2bf(v);
                    z2h[row * 264 + n] = (short)hi;
                    z2l[row * 264 + n] = (short)f2bf(v - bf2f(hi));
                }
            }
        }
        __syncthreads();

        // ---- C: m = tanh(z2 W3^T[n-slice] + b3), W3 B-frags straight from global (L2) ----
        {
            const int mt = wv >> 1, nb = (wv & 1) * 9;   // 9 n-tiles per wave
            f32x4 acc[9];
#pragma unroll
            for (int i = 0; i < 9; ++i) acc[i] = zero4;
            short8 bh[9], bl[9];
#pragma unroll
            for (int i = 0; i < 9; ++i) {                // prefetch kk=0
                long n = n0 + (nb + i) * 16 + l15;
                bh[i] = *(const short8*)(const void*)(w3h + n * 256 + quad * 8);
                bl[i] = *(const short8*)(const void*)(w3l + n * 256 + quad * 8);
            }
            for (int kk = 0; kk < 8; ++kk) {
                short8 ah = *(const short8*)(const void*)&z2h[(mt * 16 + l15) * 264 + kk * 32 + quad * 8];
                short8 al = *(const short8*)(const void*)&z2l[(mt * 16 + l15) * 264 + kk * 32 + quad * 8];
                short8 nh[9], nl[9];
                if (kk < 7) {
#pragma unroll
                    for (int i = 0; i < 9; ++i) {
                        long n = n0 + (nb + i) * 16 + l15;
                        nh[i] = *(const short8*)(const void*)(w3h + n * 256 + (kk + 1) * 32 + quad * 8);
                        nl[i] = *(const short8*)(const void*)(w3l + n * 256 + (kk + 1) * 32 + quad * 8);
                    }
                }
#pragma unroll
                for (int i = 0; i < 9; ++i) {
                    acc[i] = __builtin_amdgcn_mfma_f32_16x16x32_bf16(ah, bh[i], acc[i], 0, 0, 0);
                    acc[i] = __builtin_amdgcn_mfma_f32_16x16x32_bf16(ah, bl[i], acc[i], 0, 0, 0);
                    acc[i] = __builtin_amdgcn_mfma_f32_16x16x32_bf16(al, bh[i], acc[i], 0, 0, 0);
                }
#pragma unroll
                for (int i = 0; i < 9; ++i) { bh[i] = nh[i]; bl[i] = nl[i]; }
            }
            // epilogue: tanh -> ml (2-way-bank pattern, conflict-free)
#pragma unroll
            for (int i = 0; i < 9; ++i) {
                int lc = (nb + i) * 16 + l15;            // 0..287 local col
                float bias = vb3[n0 + lc];
#pragma unroll
                for (int r = 0; r < 4; ++r) {
                    int row = mt * 16 + quad * 4 + r;
                    ml[row * 296 + lc] = tanh_f(acc[i][r] + bias);
                }
            }
        }
        __syncthreads();

        // ---- l-contraction + h slice update + publish ----
        {
            int row = tid >> 3, sr = tid & 7;
            const f32x4* mp = (const f32x4*)(const void*)&ml[row * 296 + sr * 36];
            const f32x4* lp = (const f32x4*)(const void*)&lss[row * 40];
            float a = 0.f;
#pragma unroll
            for (int q = 0; q < 9; ++q) {
                f32x4 m4 = mp[q], l4 = lp[q];
                a += m4[0] * l4[0] + m4[1] * l4[1] + m4[2] * l4[2] + m4[3] * l4[3];
            }
            hloc[tid] += a;
        }
        __syncthreads();
        if ((tid & 1) == 0) {           // publish pairs (exclusive owner)
            int row = tid >> 3, sr = tid & 7;
            U64F2 p; p.f[0] = hloc[tid]; p.f[1] = hloc[tid + 1];
            stg64(h + (long)(b0 + row) * 256 + s0 + sr, p.u);
        }

        // ---- group barrier (32 arrivals, group-private lines, monotone counters) ----
        __syncthreads();
        if (tid == 0) {
            int old = __hip_atomic_fetch_add(garr, 1, __ATOMIC_RELAXED, __HIP_MEMORY_SCOPE_AGENT);
            if (old == (t + 1) * GB - 1)
                __hip_atomic_store(grel, t + 1, __ATOMIC_RELAXED, __HIP_MEMORY_SCOPE_AGENT);
            while (__hip_atomic_load(grel, __ATOMIC_RELAXED, __HIP_MEMORY_SCOPE_AGENT) < t + 1)
                __builtin_amdgcn_s_sleep(1);
        }
        __syncthreads();
    }

    // ---- final readout out[rowR, 512, :] ----
    if (tid < 128) {
        U64F2 v; v.u = ldg64(h + (long)rowR * 256 + tid * 2);
        hrow[tid * 2] = v.f[0]; hrow[tid * 2 + 1] = v.f[1];
    }
    __syncthreads();
    if (tid < OUTd) {
        float acc = rob[tid];
        const float* wp = roW + tid * 256;
        for (int s = 0; s < 256; s += 4) {
            f32x4 hv = *(const f32x4*)(const void*)&hrow[s];
            f32x4 w4 = *(const f32x4*)(wp + s);
            acc += hv[0] * w4[0] + hv[1] * w4[1] + hv[2] * w4[2] + hv[3] * w4[3];
        }
        out[((long)rowR * 513 + Tt) * OUTd + tid] = acc;
    }
}

extern "C" void kernel_launch(void* const* d_in, const int* in_sizes, int n_in,
                              void* d_out, int out_size, void* d_ws, size_t ws_size,
                              hipStream_t stream) {
    const float* x0      = (const float*)d_in[0];
    const float* logsigs = (const float*)d_in[1];
    const float* iW1 = (const float*)d_in[2];
    const float* ib1 = (const float*)d_in[3];
    const float* iW2 = (const float*)d_in[4];
    const float* ib2 = (const float*)d_in[5];
    const float* iW3 = (const float*)d_in[6];
    const float* ib3 = (const float*)d_in[7];
    const float* vW1 = (const float*)d_in[8];
    const float* vb1 = (const float*)d_in[9];
    const float* vW2 = (const float*)d_in[10];
    const float* vb2 = (const float*)d_in[11];
    const float* vW3 = (const float*)d_in[12];
    const float* vb3 = (const float*)d_in[13];
    const float* roW = (const float*)d_in[14];
    const float* rob = (const float*)d_in[15];
    float* out = (float*)d_out;

    char* p = (char*)d_ws;
    float* h             = (float*)p;                         // 262144 B
    unsigned short* w1h  = (unsigned short*)(p + 262144);     // 131072 B
    unsigned short* w1l  = (unsigned short*)(p + 393216);     // 131072 B
    unsigned short* w2h  = (unsigned short*)(p + 524288);     // 131072 B
    unsigned short* w2l  = (unsigned short*)(p + 655360);     // 131072 B
    unsigned short* w3h  = (unsigned short*)(p + 786432);     // 4718592 B
    unsigned short* w3l  = (unsigned short*)(p + 5505024);    // 4718592 B
    int* bar             = (int*)(p + 10223616);              // 2048 B

    hipMemsetAsync(bar, 0, 2048, stream);
    prep_kernel<<<dim3(256), dim3(256), 0, stream>>>(
        x0, iW1, ib1, iW2, ib2, iW3, ib3, vW1, vW2, vW3,
        h, w1h, w1l, w2h, w2l, w3h, w3l);
    scan_kernel<<<dim3(256), dim3(256), 0, stream>>>(
        logsigs, vb1, vb2, vb3, roW, rob,
        w1h, w1l, w2h, w2l, w3h, w3l, out, h, bar);
}

// Round 7
// 59041.528 us; speedup vs baseline: 1.4406x; 1.4406x over previous
//
#include <hip/hip_runtime.h>

// Problem constants (B,T,S,L,D_IN,OUT,W = 256,512,256,36,8,10,256)
#define Tt   512
#define Ll   36
#define DIN  8
#define OUTd 10
#define GB   32    // blocks per group (8 groups x 32 blocks)

typedef __attribute__((ext_vector_type(8))) short short8;
typedef __attribute__((ext_vector_type(4))) float f32x4;

__device__ __forceinline__ unsigned short f2bf(float f) {
    union { float f; unsigned int u; } v; v.f = f;
    unsigned int r = v.u + 0x7fffu + ((v.u >> 16) & 1u);   // RNE
    return (unsigned short)(r >> 16);
}
__device__ __forceinline__ float bf2f(unsigned short u) {
    union { unsigned int u; float f; } v; v.u = ((unsigned int)u) << 16;
    return v.f;
}
__device__ __forceinline__ float sp_f(float x) {      // jax.nn.softplus
    return fmaxf(x, 0.f) + __logf(1.f + __expf(-fabsf(x)));
}
__device__ __forceinline__ float tanh_f(float x) {
    float e = __expf(2.f * x);
    return 1.f - 2.f / (e + 1.f);
}

// ---- agent-scope (sc1 / LLC-coherent) helpers for cross-block data (h, barrier) ----
__device__ __forceinline__ unsigned long long ldg64(const void* p) {
    return __hip_atomic_load((const unsigned long long*)p, __ATOMIC_RELAXED, __HIP_MEMORY_SCOPE_AGENT);
}
__device__ __forceinline__ float ldgf(const float* p) {
    return __hip_atomic_load(p, __ATOMIC_RELAXED, __HIP_MEMORY_SCOPE_AGENT);
}
__device__ __forceinline__ void stg64(void* p, unsigned long long v) {
    __hip_atomic_store((unsigned long long*)p, v, __ATOMIC_RELAXED, __HIP_MEMORY_SCOPE_AGENT);
}
union U64F2 { unsigned long long u; float f[2]; unsigned short s[4]; };

__device__ __forceinline__ void cast_quad2(const float* src, unsigned short* dh,
                                           unsigned short* dl, long u) {
    f32x4 f = *(const f32x4*)(src + u * 4);
    U64F2 H, L;
#pragma unroll
    for (int q = 0; q < 4; ++q) {
        float v = f[q];
        unsigned short hi = f2bf(v);
        H.s[q] = hi;
        L.s[q] = f2bf(v - bf2f(hi));
    }
    *(unsigned long long*)(dh + u * 4) = H.u;
    *(unsigned long long*)(dl + u * 4) = L.u;
}

// ================= prep: init MLP (blk<8), W1/W2 hi/lo (8..15), W3 hi/lo (16..255) ====
__global__ __launch_bounds__(256) void prep_kernel(
    const float* __restrict__ x0,
    const float* __restrict__ iW1, const float* __restrict__ ib1,
    const float* __restrict__ iW2, const float* __restrict__ ib2,
    const float* __restrict__ iW3, const float* __restrict__ ib3,
    const float* __restrict__ vW1, const float* __restrict__ vW2,
    const float* __restrict__ vW3,
    float* __restrict__ h,
    unsigned short* __restrict__ w1h, unsigned short* __restrict__ w1l,
    unsigned short* __restrict__ w2h, unsigned short* __restrict__ w2l,
    unsigned short* __restrict__ w3h, unsigned short* __restrict__ w3l) {
    const int tid = threadIdx.x, blk = blockIdx.x;
    if (blk < 8) {
        __shared__ float x0s[32][DIN];
        __shared__ float h1[32 * 257];
        __shared__ float h2[32 * 257];
        const int b0 = blk * 32;
        x0s[tid >> 3][tid & 7] = x0[(b0 + (tid >> 3)) * DIN + (tid & 7)];
        __syncthreads();
        const int j = tid;
        {
            float w[DIN];
#pragma unroll
            for (int k = 0; k < DIN; ++k) w[k] = iW1[j * DIN + k];
            float bias = ib1[j];
            for (int r = 0; r < 32; ++r) {
                float acc = bias;
#pragma unroll
                for (int k = 0; k < DIN; ++k) acc += x0s[r][k] * w[k];
                h1[r * 257 + j] = sp_f(acc);
            }
        }
        __syncthreads();
        {
            float bias = ib2[j];
            for (int rb = 0; rb < 4; ++rb) {
                float a8[8];
#pragma unroll
                for (int rr = 0; rr < 8; ++rr) a8[rr] = bias;
                for (int k = 0; k < 256; ++k) {
                    float wv = iW2[j * 256 + k];
#pragma unroll
                    for (int rr = 0; rr < 8; ++rr) a8[rr] += h1[(rb * 8 + rr) * 257 + k] * wv;
                }
#pragma unroll
                for (int rr = 0; rr < 8; ++rr) h2[(rb * 8 + rr) * 257 + j] = sp_f(a8[rr]);
            }
        }
        __syncthreads();
        {
            float bias = ib3[j];
            for (int rb = 0; rb < 4; ++rb) {
                float a8[8];
#pragma unroll
                for (int rr = 0; rr < 8; ++rr) a8[rr] = bias;
                for (int k = 0; k < 256; ++k) {
                    float wv = iW3[j * 256 + k];
#pragma unroll
                    for (int rr = 0; rr < 8; ++rr) a8[rr] += h2[(rb * 8 + rr) * 257 + k] * wv;
                }
#pragma unroll
                for (int rr = 0; rr < 8; ++rr)
                    h[(b0 + rb * 8 + rr) * 256 + j] = a8[rr];
            }
        }
    } else if (blk < 16) {
        const int idx = blk - 8;                 // 0..3: W1 parts, 4..7: W2 parts
        const float* src = (idx < 4) ? vW1 : vW2;
        unsigned short* dh = (idx < 4) ? w1h : w2h;
        unsigned short* dl = (idx < 4) ? w1l : w2l;
        const int part = idx & 3;
        for (int u = part * 4096 + tid; u < (part + 1) * 4096; u += 256)
            cast_quad2(src, dh, dl, u);
    } else {
        for (long u = (long)(blk - 16) * 256 + tid; u < 589824; u += 240L * 256)
            cast_quad2(vW3, w3h, w3l, u);
    }
}

// ---- z-layer pass: NT n-tiles/wave, hi/lo A (LDS) x hi/lo B (global/L2), 3-MFMA emulation,
//      softplus + hi/lo split output to LDS. Cross-kk double-buffer on B. ----
template <int NT>
__device__ __forceinline__ void layerpass(
    const unsigned short* __restrict__ wbh, const unsigned short* __restrict__ wbl,
    const float* __restrict__ bias,
    const short* __restrict__ sH, const short* __restrict__ sL,
    short* __restrict__ dH, short* __restrict__ dL, int ntoff, int wv, int lane) {
    const int quad = lane >> 4, l15 = lane & 15;
    const int mt = wv >> 1, nb = (wv & 1) * 8 + ntoff;
    const f32x4 zero4 = {0.f, 0.f, 0.f, 0.f};
    f32x4 acc[NT];
#pragma unroll
    for (int i = 0; i < NT; ++i) acc[i] = zero4;
    short8 bhc[NT], blc[NT], bhn[NT], bln[NT];
#pragma unroll
    for (int i = 0; i < NT; ++i) {
        int n = (nb + i) * 16 + l15;
        bhc[i] = *(const short8*)(const void*)(wbh + n * 256 + quad * 8);
        blc[i] = *(const short8*)(const void*)(wbl + n * 256 + quad * 8);
    }
    for (int kk = 0; kk < 8; ++kk) {
        short8 ah = *(const short8*)(const void*)&sH[(mt * 16 + l15) * 264 + kk * 32 + quad * 8];
        short8 al = *(const short8*)(const void*)&sL[(mt * 16 + l15) * 264 + kk * 32 + quad * 8];
        if (kk < 7) {
#pragma unroll
            for (int i = 0; i < NT; ++i) {
                int n = (nb + i) * 16 + l15;
                bhn[i] = *(const short8*)(const void*)(wbh + n * 256 + (kk + 1) * 32 + quad * 8);
                bln[i] = *(const short8*)(const void*)(wbl + n * 256 + (kk + 1) * 32 + quad * 8);
            }
        }
#pragma unroll
        for (int i = 0; i < NT; ++i) {
            acc[i] = __builtin_amdgcn_mfma_f32_16x16x32_bf16(ah, bhc[i], acc[i], 0, 0, 0);
            acc[i] = __builtin_amdgcn_mfma_f32_16x16x32_bf16(ah, blc[i], acc[i], 0, 0, 0);
            acc[i] = __builtin_amdgcn_mfma_f32_16x16x32_bf16(al, bhc[i], acc[i], 0, 0, 0);
        }
#pragma unroll
        for (int i = 0; i < NT; ++i) { bhc[i] = bhn[i]; blc[i] = bln[i]; }
    }
#pragma unroll
    for (int i = 0; i < NT; ++i) {
        int n = (nb + i) * 16 + l15;
        float b = bias[n];
#pragma unroll
        for (int r = 0; r < 4; ++r) {
            int row = mt * 16 + quad * 4 + r;
            float v = sp_f(acc[i][r] + b);
            unsigned short hi = f2bf(v);
            dH[row * 264 + n] = (short)hi;
            dL[row * 264 + n] = (short)f2bf(v - bf2f(hi));
        }
    }
}

// ---- C-phase pass: NT n-tiles/wave, W3 hi/lo direct from global(L2), cross-kk dbuf ----
template <int NT>
__device__ __forceinline__ void cpass(
    const unsigned short* __restrict__ w3h, const unsigned short* __restrict__ w3l,
    const float* __restrict__ vb3,
    const short* __restrict__ z2H, const short* __restrict__ z2L,
    float* __restrict__ ml, long n0, int ntoff, int wv, int lane) {
    const int quad = lane >> 4, l15 = lane & 15;
    const int mt = wv >> 1;
    const int nb = (wv & 1) * 9 + ntoff;
    const f32x4 zero4 = {0.f, 0.f, 0.f, 0.f};
    f32x4 acc[NT];
#pragma unroll
    for (int i = 0; i < NT; ++i) acc[i] = zero4;
    short8 bhc[NT], blc[NT], bhn[NT], bln[NT];
#pragma unroll
    for (int i = 0; i < NT; ++i) {
        long n = n0 + (nb + i) * 16 + l15;
        bhc[i] = *(const short8*)(const void*)(w3h + n * 256 + quad * 8);
        blc[i] = *(const short8*)(const void*)(w3l + n * 256 + quad * 8);
    }
    for (int kk = 0; kk < 8; ++kk) {
        short8 ah = *(const short8*)(const void*)&z2H[(mt * 16 + l15) * 264 + kk * 32 + quad * 8];
        short8 al = *(const short8*)(const void*)&z2L[(mt * 16 + l15) * 264 + kk * 32 + quad * 8];
        if (kk < 7) {
#pragma unroll
            for (int i = 0; i < NT; ++i) {
                long n = n0 + (nb + i) * 16 + l15;
                bhn[i] = *(const short8*)(const void*)(w3h + n * 256 + (kk + 1) * 32 + quad * 8);
                bln[i] = *(const short8*)(const void*)(w3l + n * 256 + (kk + 1) * 32 + quad * 8);
            }
        }
#pragma unroll
        for (int i = 0; i < NT; ++i) {
            acc[i] = __builtin_amdgcn_mfma_f32_16x16x32_bf16(ah, bhc[i], acc[i], 0, 0, 0);
            acc[i] = __builtin_amdgcn_mfma_f32_16x16x32_bf16(ah, blc[i], acc[i], 0, 0, 0);
            acc[i] = __builtin_amdgcn_mfma_f32_16x16x32_bf16(al, bhc[i], acc[i], 0, 0, 0);
        }
#pragma unroll
        for (int i = 0; i < NT; ++i) { bhc[i] = bhn[i]; blc[i] = bln[i]; }
    }
#pragma unroll
    for (int i = 0; i < NT; ++i) {
        int lc = (nb + i) * 16 + l15;
        float b = vb3[n0 + lc];
#pragma unroll
        for (int r = 0; r < 4; ++r) {
            int row = mt * 16 + quad * 4 + r;
            ml[row * 292 + lc] = tanh_f(acc[i][r] + b);
        }
    }
}

// ================= scan: 256 blocks = 8 groups x 32; one group barrier per step =========
__global__ __launch_bounds__(256, 1) void scan_kernel(
    const float* __restrict__ logsigs,
    const float* __restrict__ vb1, const float* __restrict__ vb2,
    const float* __restrict__ vb3,
    const float* __restrict__ roW, const float* __restrict__ rob,
    const unsigned short* __restrict__ w1h, const unsigned short* __restrict__ w1l,
    const unsigned short* __restrict__ w2h, const unsigned short* __restrict__ w2l,
    const unsigned short* __restrict__ w3h, const unsigned short* __restrict__ w3l,
    float* __restrict__ out, float* h, int* bar) {
    __shared__ short bufA[2][32 * 264];          // h hi/lo, later z2 hi/lo
    __shared__ float bufBf[32 * 292];            // z1 hi/lo (as shorts), later ml (f32)
    __shared__ float lss[32 * 40];
    __shared__ float hloc[256];                  // exclusive h slice: 32 rows x 8 s
    __shared__ float hrow[256];                  // readout row (fp32)

    short* const hlh = bufA[0];  short* const hll = bufA[1];
    short* const z2h = bufA[0];  short* const z2l = bufA[1];
    short* const z1h = (short*)bufBf;
    short* const z1l = z1h + 32 * 264;
    float* const ml  = bufBf;

    const int tid = threadIdx.x, blk = blockIdx.x;
    const int lane = tid & 63, wv = tid >> 6;
    const int g = blk >> 5, j = blk & 31;       // j%8 XCD-affine => 4 W3 slices per XCD L2
    const int b0 = g * 32;                       // group batch base
    const long n0 = (long)j * 288;               // W3 n-slice base
    const int s0 = j * 8;                        // owned s-slice base
    const int rowR = b0 + j;                     // readout row
    int* const garr = bar + g * 128;
    int* const grel = garr + 64;

    // initial exclusive h slice from h0
    {
        int row = tid >> 3, sr = tid & 7;
        hloc[tid] = ldgf(h + (b0 + row) * 256 + s0 + sr);
    }

    for (int t = 0; t < Tt; ++t) {
        // ---- gather h (sc1/LLC) + hi/lo split; stage hrow; stage lss ----
        for (int i = tid; i < 4096; i += 256) {
            int r = i >> 7, c = (i & 127) * 2;
            U64F2 v; v.u = ldg64(h + (b0 + r) * 256 + c);
#pragma unroll
            for (int q = 0; q < 2; ++q) {
                float f = v.f[q];
                unsigned short hi = f2bf(f);
                hlh[r * 264 + c + q] = (short)hi;
                hll[r * 264 + c + q] = (short)f2bf(f - bf2f(hi));
            }
        }
        if (tid < 128) {
            U64F2 v; v.u = ldg64(h + (long)rowR * 256 + tid * 2);
            hrow[tid * 2] = v.f[0]; hrow[tid * 2 + 1] = v.f[1];
        }
        for (int i = tid; i < 32 * Ll; i += 256) {
            int r = i / Ll, l = i - r * Ll;
            lss[r * 40 + l] = logsigs[((long)(b0 + r) * Tt + t) * Ll + l];
        }
        __syncthreads();

        // ---- z1 = sp(h W1^T) -> bufB (two register-safe passes) ----
        layerpass<4>(w1h, w1l, vb1, hlh, hll, z1h, z1l, 0, wv, lane);
        layerpass<4>(w1h, w1l, vb1, hlh, hll, z1h, z1l, 4, wv, lane);
        __syncthreads();
        // ---- z2 = sp(z1 W2^T) -> bufA (h staging dead) ----
        layerpass<4>(w2h, w2l, vb2, z1h, z1l, z2h, z2l, 0, wv, lane);
        layerpass<4>(w2h, w2l, vb2, z1h, z1l, z2h, z2l, 4, wv, lane);
        __syncthreads();
        // ---- C: m = tanh(z2 W3^T + b3) for n-slice, two register-safe passes -> ml ----
        cpass<5>(w3h, w3l, vb3, z2h, z2l, ml, n0, 0, wv, lane);
        cpass<4>(w3h, w3l, vb3, z2h, z2l, ml, n0, 5, wv, lane);
        __syncthreads();

        // ---- l-contraction: thread owns one (row, sr) ----
        {
            int row = tid >> 3, sr = tid & 7;
            const f32x4* mp = (const f32x4*)(const void*)&ml[row * 292 + sr * 36];
            const f32x4* lp = (const f32x4*)(const void*)&lss[row * 40];
            float a = 0.f;
#pragma unroll
            for (int q = 0; q < 9; ++q) {
                f32x4 m4 = mp[q], l4 = lp[q];
                a += m4[0] * l4[0] + m4[1] * l4[1] + m4[2] * l4[2] + m4[3] * l4[3];
            }
            hloc[tid] += a;
        }
        __syncthreads();
        if ((tid & 1) == 0) {                    // publish pairs (exclusive owner)
            int row = tid >> 3, sr = tid & 7;
            U64F2 p; p.f[0] = hloc[tid]; p.f[1] = hloc[tid + 1];
            stg64(h + (long)(b0 + row) * 256 + s0 + sr, p.u);
        }

        // ---- readout out[rowR, t, :] (h_t, exact fp32) — overlaps barrier wait ----
        if (tid < OUTd) {
            float acc = rob[tid];
            const float* wp = roW + tid * 256;
            for (int s = 0; s < 256; s += 4) {
                f32x4 hv = *(const f32x4*)(const void*)&hrow[s];
                f32x4 w4 = *(const f32x4*)(wp + s);
                acc += hv[0] * w4[0] + hv[1] * w4[1] + hv[2] * w4[2] + hv[3] * w4[3];
            }
            out[((long)rowR * 513 + t) * OUTd + tid] = acc;
        }

        // ---- group barrier (32 arrivals, monotone counters, tid0-only poll) ----
        __syncthreads();
        if (tid == 0) {
            int old = __hip_atomic_fetch_add(garr, 1, __ATOMIC_RELAXED, __HIP_MEMORY_SCOPE_AGENT);
            if (old == (t + 1) * GB - 1)
                __hip_atomic_store(grel, t + 1, __ATOMIC_RELAXED, __HIP_MEMORY_SCOPE_AGENT);
            while (__hip_atomic_load(grel, __ATOMIC_RELAXED, __HIP_MEMORY_SCOPE_AGENT) < t + 1)
                __builtin_amdgcn_s_sleep(1);
        }
        __syncthreads();
    }

    // ---- final readout out[rowR, 512, :] ----
    if (tid < 128) {
        U64F2 v; v.u = ldg64(h + (long)rowR * 256 + tid * 2);
        hrow[tid * 2] = v.f[0]; hrow[tid * 2 + 1] = v.f[1];
    }
    __syncthreads();
    if (tid < OUTd) {
        float acc = rob[tid];
        const float* wp = roW + tid * 256;
        for (int s = 0; s < 256; s += 4) {
            f32x4 hv = *(const f32x4*)(const void*)&hrow[s];
            f32x4 w4 = *(const f32x4*)(wp + s);
            acc += hv[0] * w4[0] + hv[1] * w4[1] + hv[2] * w4[2] + hv[3] * w4[3];
        }
        out[((long)rowR * 513 + Tt) * OUTd + tid] = acc;
    }
}

extern "C" void kernel_launch(void* const* d_in, const int* in_sizes, int n_in,
                              void* d_out, int out_size, void* d_ws, size_t ws_size,
                              hipStream_t stream) {
    const float* x0      = (const float*)d_in[0];
    const float* logsigs = (const float*)d_in[1];
    const float* iW1 = (const float*)d_in[2];
    const float* ib1 = (const float*)d_in[3];
    const float* iW2 = (const float*)d_in[4];
    const float* ib2 = (const float*)d_in[5];
    const float* iW3 = (const float*)d_in[6];
    const float* ib3 = (const float*)d_in[7];
    const float* vW1 = (const float*)d_in[8];
    const float* vb1 = (const float*)d_in[9];
    const float* vW2 = (const float*)d_in[10];
    const float* vb2 = (const float*)d_in[11];
    const float* vW3 = (const float*)d_in[12];
    const float* vb3 = (const float*)d_in[13];
    const float* roW = (const float*)d_in[14];
    const float* rob = (const float*)d_in[15];
    float* out = (float*)d_out;

    char* p = (char*)d_ws;
    float* h            = (float*)p;                        // 262144 B
    unsigned short* w1h = (unsigned short*)(p + 262144);    // 131072 B
    unsigned short* w1l = (unsigned short*)(p + 393216);    // 131072 B
    unsigned short* w2h = (unsigned short*)(p + 524288);    // 131072 B
    unsigned short* w2l = (unsigned short*)(p + 655360);    // 131072 B
    unsigned short* w3h = (unsigned short*)(p + 786432);    // 4718592 B
    unsigned short* w3l = (unsigned short*)(p + 5505024);   // 4718592 B
    int* bar            = (int*)(p + 10223616);             // 4096 B

    hipMemsetAsync(bar, 0, 4096, stream);
    prep_kernel<<<dim3(256), dim3(256), 0, stream>>>(
        x0, iW1, ib1, iW2, ib2, iW3, ib3, vW1, vW2, vW3,
        h, w1h, w1l, w2h, w2l, w3h, w3l);
    scan_kernel<<<dim3(256), dim3(256), 0, stream>>>(
        logsigs, vb1, vb2, vb3, roW, rob,
        w1h, w1l, w2h, w2l, w3h, w3l, out, h, bar);
}

// Round 8
// 29617.148 us; speedup vs baseline: 2.8719x; 1.9935x over previous
//
#include <hip/hip_runtime.h>

// Problem constants (B,T,S,L,D_IN,OUT,W = 256,512,256,36,8,10,256)
#define Tt   512
#define Ll   36
#define DIN  8
#define OUTd 10

typedef __attribute__((ext_vector_type(8))) short short8;
typedef __attribute__((ext_vector_type(4))) float f32x4;

__device__ __forceinline__ unsigned short f2bf(float f) {
    union { float f; unsigned int u; } v; v.f = f;
    unsigned int r = v.u + 0x7fffu + ((v.u >> 16) & 1u);   // RNE
    return (unsigned short)(r >> 16);
}
__device__ __forceinline__ float bf2f(unsigned short u) {
    union { unsigned int u; float f; } v; v.u = ((unsigned int)u) << 16;
    return v.f;
}
__device__ __forceinline__ float sp_f(float x) {      // jax.nn.softplus
    return fmaxf(x, 0.f) + __logf(1.f + __expf(-fabsf(x)));
}
__device__ __forceinline__ float tanh_f(float x) {
    float e = __expf(2.f * x);
    return 1.f - 2.f / (e + 1.f);
}
union U64F2 { unsigned long long u; float f[2]; unsigned short s[4]; };

__device__ __forceinline__ void cast_quad2(const float* src, unsigned short* dh,
                                           unsigned short* dl, long u) {
    f32x4 f = *(const f32x4*)(src + u * 4);
    U64F2 H, L;
#pragma unroll
    for (int q = 0; q < 4; ++q) {
        float v = f[q];
        unsigned short hi = f2bf(v);
        H.s[q] = hi;
        L.s[q] = f2bf(v - bf2f(hi));
    }
    *(unsigned long long*)(dh + u * 4) = H.u;
    *(unsigned long long*)(dl + u * 4) = L.u;
}

// ================= prep: init MLP (blk<8), W1/W2 hi/lo (8..15), W3 hi/lo (16..255) ====
__global__ __launch_bounds__(256) void prep_kernel(
    const float* __restrict__ x0,
    const float* __restrict__ iW1, const float* __restrict__ ib1,
    const float* __restrict__ iW2, const float* __restrict__ ib2,
    const float* __restrict__ iW3, const float* __restrict__ ib3,
    const float* __restrict__ vW1, const float* __restrict__ vW2,
    const float* __restrict__ vW3,
    float* __restrict__ h0,
    unsigned short* __restrict__ w1h, unsigned short* __restrict__ w1l,
    unsigned short* __restrict__ w2h, unsigned short* __restrict__ w2l,
    unsigned short* __restrict__ w3h, unsigned short* __restrict__ w3l) {
    const int tid = threadIdx.x, blk = blockIdx.x;
    if (blk < 8) {
        __shared__ float x0s[32][DIN];
        __shared__ float h1[32 * 257];
        __shared__ float h2[32 * 257];
        const int b0 = blk * 32;
        x0s[tid >> 3][tid & 7] = x0[(b0 + (tid >> 3)) * DIN + (tid & 7)];
        __syncthreads();
        const int j = tid;
        {
            float w[DIN];
#pragma unroll
            for (int k = 0; k < DIN; ++k) w[k] = iW1[j * DIN + k];
            float bias = ib1[j];
            for (int r = 0; r < 32; ++r) {
                float acc = bias;
#pragma unroll
                for (int k = 0; k < DIN; ++k) acc += x0s[r][k] * w[k];
                h1[r * 257 + j] = sp_f(acc);
            }
        }
        __syncthreads();
        {
            float bias = ib2[j];
            for (int rb = 0; rb < 4; ++rb) {
                float a8[8];
#pragma unroll
                for (int rr = 0; rr < 8; ++rr) a8[rr] = bias;
                for (int k = 0; k < 256; ++k) {
                    float wv = iW2[j * 256 + k];
#pragma unroll
                    for (int rr = 0; rr < 8; ++rr) a8[rr] += h1[(rb * 8 + rr) * 257 + k] * wv;
                }
#pragma unroll
                for (int rr = 0; rr < 8; ++rr) h2[(rb * 8 + rr) * 257 + j] = sp_f(a8[rr]);
            }
        }
        __syncthreads();
        {
            float bias = ib3[j];
            for (int rb = 0; rb < 4; ++rb) {
                float a8[8];
#pragma unroll
                for (int rr = 0; rr < 8; ++rr) a8[rr] = bias;
                for (int k = 0; k < 256; ++k) {
                    float wv = iW3[j * 256 + k];
#pragma unroll
                    for (int rr = 0; rr < 8; ++rr) a8[rr] += h2[(rb * 8 + rr) * 257 + k] * wv;
                }
#pragma unroll
                for (int rr = 0; rr < 8; ++rr)
                    h0[(b0 + rb * 8 + rr) * 256 + j] = a8[rr];
            }
        }
    } else if (blk < 16) {
        const int idx = blk - 8;                 // 0..3: W1 parts, 4..7: W2 parts
        const float* src = (idx < 4) ? vW1 : vW2;
        unsigned short* dh = (idx < 4) ? w1h : w2h;
        unsigned short* dl = (idx < 4) ? w1l : w2l;
        const int part = idx & 3;
        for (int u = part * 4096 + tid; u < (part + 1) * 4096; u += 256)
            cast_quad2(src, dh, dl, u);
    } else {
        for (long u = (long)(blk - 16) * 256 + tid; u < 589824; u += 240L * 256)
            cast_quad2(vW3, w3h, w3l, u);
    }
}

// ---- z-layer: 8 n-tiles/wave, hi/lo A (LDS) x hi/lo B (in-loop loads from L2),
//      3-MFMA emulation, softplus + hi/lo split out. NO manual prefetch arrays (VGPR-safe). ----
__device__ __forceinline__ void layer8(
    const unsigned short* __restrict__ wh, const unsigned short* __restrict__ wl,
    const float* __restrict__ bias,
    const short* __restrict__ sH, const short* __restrict__ sL,
    short* __restrict__ dH, short* __restrict__ dL, int wv, int lane) {
    const int quad = lane >> 4, l15 = lane & 15;
    const int mt = wv >> 1, nb = (wv & 1) * 8;
    const f32x4 zero4 = {0.f, 0.f, 0.f, 0.f};
    f32x4 acc[8] = {zero4, zero4, zero4, zero4, zero4, zero4, zero4, zero4};
    for (int k0 = 0; k0 < 256; k0 += 32) {
        short8 ah = *(const short8*)(const void*)&sH[(mt * 16 + l15) * 264 + k0 + quad * 8];
        short8 al = *(const short8*)(const void*)&sL[(mt * 16 + l15) * 264 + k0 + quad * 8];
#pragma unroll
        for (int i = 0; i < 8; ++i) {
            int n = (nb + i) * 16 + l15;
            short8 bh = *(const short8*)(const void*)(wh + n * 256 + k0 + quad * 8);
            short8 bl = *(const short8*)(const void*)(wl + n * 256 + k0 + quad * 8);
            acc[i] = __builtin_amdgcn_mfma_f32_16x16x32_bf16(ah, bh, acc[i], 0, 0, 0);
            acc[i] = __builtin_amdgcn_mfma_f32_16x16x32_bf16(ah, bl, acc[i], 0, 0, 0);
            acc[i] = __builtin_amdgcn_mfma_f32_16x16x32_bf16(al, bh, acc[i], 0, 0, 0);
        }
    }
#pragma unroll
    for (int i = 0; i < 8; ++i) {
        int n = (nb + i) * 16 + l15;
        float b = bias[n];
#pragma unroll
        for (int r = 0; r < 4; ++r) {
            int row = mt * 16 + quad * 4 + r;
            float v = sp_f(acc[i][r] + b);
            unsigned short hi = f2bf(v);
            dH[row * 264 + n] = (short)hi;
            dL[row * 264 + n] = (short)f2bf(v - bf2f(hi));
        }
    }
}

// ================= step: 256 blocks; block = (group rows 32) x (W3 n-slice 288 = 8 s) ======
__global__ __launch_bounds__(256, 1) void step_kernel(
    const float* __restrict__ hin, float* __restrict__ hout,
    const float* __restrict__ logsigs,
    const float* __restrict__ vb1, const float* __restrict__ vb2,
    const float* __restrict__ vb3,
    const float* __restrict__ roW, const float* __restrict__ rob,
    const unsigned short* __restrict__ w1h, const unsigned short* __restrict__ w1l,
    const unsigned short* __restrict__ w2h, const unsigned short* __restrict__ w2l,
    const unsigned short* __restrict__ w3h, const unsigned short* __restrict__ w3l,
    float* __restrict__ out, int t) {
    __shared__ short bufA[2][32 * 264];          // h hi/lo, later z2 hi/lo
    __shared__ float bufBf[32 * 292];            // z1 hi/lo (shorts), later ml (f32)
    __shared__ float lss[32 * 40];
    __shared__ float hrow[256];                  // readout row (fp32)

    short* const hlh = bufA[0];  short* const hll = bufA[1];
    short* const z2h = bufA[0];  short* const z2l = bufA[1];
    short* const z1h = (short*)bufBf;
    short* const z1l = z1h + 32 * 264;
    float* const ml  = bufBf;

    const int tid = threadIdx.x, blk = blockIdx.x;
    const int lane = tid & 63, wv = tid >> 6;
    const int quad = lane >> 4, l15 = lane & 15;
    const int g = blk >> 5, j = blk & 31;        // blk%8 == j%8 -> W3-slice XCD affinity
    const int b0 = g * 32;                       // group batch base
    const long n0 = (long)j * 288;               // W3 n-slice base
    const int s0 = j * 8;                        // owned s-slice (32B-aligned sector)
    const int rowR = b0 + j;                     // readout row

    // ---- gather h(t) (plain loads; kernel boundary = coherence) + hi/lo split ----
    for (int i = tid; i < 4096; i += 256) {
        int r = i >> 7, c = (i & 127) * 2;
        const float* hp = hin + (long)(b0 + r) * 256 + c;
        float f0 = hp[0], f1 = hp[1];
        unsigned short h0 = f2bf(f0), h1 = f2bf(f1);
        hlh[r * 264 + c]     = (short)h0;
        hll[r * 264 + c]     = (short)f2bf(f0 - bf2f(h0));
        hlh[r * 264 + c + 1] = (short)h1;
        hll[r * 264 + c + 1] = (short)f2bf(f1 - bf2f(h1));
    }
    if (tid < 128) {
        hrow[tid * 2]     = hin[(long)rowR * 256 + tid * 2];
        hrow[tid * 2 + 1] = hin[(long)rowR * 256 + tid * 2 + 1];
    }
    for (int i = tid; i < 32 * Ll; i += 256) {
        int r = i / Ll, l = i - r * Ll;
        lss[r * 40 + l] = logsigs[((long)(b0 + r) * Tt + t) * Ll + l];
    }
    __syncthreads();

    // ---- readout out[rowR, t, :] from h(t) (exact fp32) ----
    if (tid < OUTd) {
        float acc = rob[tid];
        const float* wp = roW + tid * 256;
        for (int s = 0; s < 256; s += 4) {
            f32x4 hv = *(const f32x4*)(const void*)&hrow[s];
            f32x4 w4 = *(const f32x4*)(wp + s);
            acc += hv[0] * w4[0] + hv[1] * w4[1] + hv[2] * w4[2] + hv[3] * w4[3];
        }
        out[((long)rowR * 513 + t) * OUTd + tid] = acc;
    }

    // ---- z1 = sp(h W1^T) -> bufB ----
    layer8(w1h, w1l, vb1, hlh, hll, z1h, z1l, wv, lane);
    __syncthreads();
    // ---- z2 = sp(z1 W2^T) -> bufA (h staging dead) ----
    layer8(w2h, w2l, vb2, z1h, z1l, z2h, z2l, wv, lane);
    __syncthreads();

    // ---- C: m = tanh(z2 W3^T + b3) for n-slice (9 n-tiles/wave, in-loop B loads) -> ml ----
    {
        const int mt = wv >> 1, nb = (wv & 1) * 9;
        const f32x4 zero4 = {0.f, 0.f, 0.f, 0.f};
        f32x4 acc[9];
#pragma unroll
        for (int i = 0; i < 9; ++i) acc[i] = zero4;
        for (int kk = 0; kk < 8; ++kk) {
            short8 ah = *(const short8*)(const void*)&z2h[(mt * 16 + l15) * 264 + kk * 32 + quad * 8];
            short8 al = *(const short8*)(const void*)&z2l[(mt * 16 + l15) * 264 + kk * 32 + quad * 8];
#pragma unroll
            for (int i = 0; i < 9; ++i) {
                long n = n0 + (nb + i) * 16 + l15;
                short8 bh = *(const short8*)(const void*)(w3h + n * 256 + kk * 32 + quad * 8);
                short8 bl = *(const short8*)(const void*)(w3l + n * 256 + kk * 32 + quad * 8);
                acc[i] = __builtin_amdgcn_mfma_f32_16x16x32_bf16(ah, bh, acc[i], 0, 0, 0);
                acc[i] = __builtin_amdgcn_mfma_f32_16x16x32_bf16(ah, bl, acc[i], 0, 0, 0);
                acc[i] = __builtin_amdgcn_mfma_f32_16x16x32_bf16(al, bh, acc[i], 0, 0, 0);
            }
        }
        __syncthreads();   // bufBf (z1) dead -> safe to write ml
#pragma unroll
        for (int i = 0; i < 9; ++i) {
            int lc = (nb + i) * 16 + l15;
            float b = vb3[n0 + lc];
#pragma unroll
            for (int r = 0; r < 4; ++r) {
                int row = mt * 16 + quad * 4 + r;
                ml[row * 292 + lc] = tanh_f(acc[i][r] + b);
            }
        }
    }
    __syncthreads();

    // ---- l-contraction + h(t+1) publish (exclusive 32B-aligned col-slice) ----
    {
        int row = tid >> 3, sr = tid & 7;
        const f32x4* mp = (const f32x4*)(const void*)&ml[row * 292 + sr * 36];
        const f32x4* lp = (const f32x4*)(const void*)&lss[row * 40];
        float a = 0.f;
#pragma unroll
        for (int q = 0; q < 9; ++q) {
            f32x4 m4 = mp[q], l4 = lp[q];
            a += m4[0] * l4[0] + m4[1] * l4[1] + m4[2] * l4[2] + m4[3] * l4[3];
        }
        long gi = (long)(b0 + row) * 256 + s0 + sr;
        hout[gi] = hin[gi] + a;
    }
}

// ---------------- final readout: out[:, 512, :] ----------------
__global__ __launch_bounds__(256) void readout_last(
    const float* __restrict__ h, const float* __restrict__ roW,
    const float* __restrict__ rob, float* __restrict__ out) {
    const int tid = threadIdx.x;
    const int b0 = blockIdx.x * 32;
    for (int idx = tid; idx < 32 * OUTd; idx += 256) {
        int bl = idx / OUTd, o = idx - bl * OUTd;
        float acc = rob[o];
        const float* hp = h + (long)(b0 + bl) * 256;
        const float* wp = roW + o * 256;
        for (int s = 0; s < 256; ++s) acc += hp[s] * wp[s];
        out[((long)(b0 + bl) * 513 + Tt) * OUTd + o] = acc;
    }
}

extern "C" void kernel_launch(void* const* d_in, const int* in_sizes, int n_in,
                              void* d_out, int out_size, void* d_ws, size_t ws_size,
                              hipStream_t stream) {
    const float* x0      = (const float*)d_in[0];
    const float* logsigs = (const float*)d_in[1];
    const float* iW1 = (const float*)d_in[2];
    const float* ib1 = (const float*)d_in[3];
    const float* iW2 = (const float*)d_in[4];
    const float* ib2 = (const float*)d_in[5];
    const float* iW3 = (const float*)d_in[6];
    const float* ib3 = (const float*)d_in[7];
    const float* vW1 = (const float*)d_in[8];
    const float* vb1 = (const float*)d_in[9];
    const float* vW2 = (const float*)d_in[10];
    const float* vb2 = (const float*)d_in[11];
    const float* vW3 = (const float*)d_in[12];
    const float* vb3 = (const float*)d_in[13];
    const float* roW = (const float*)d_in[14];
    const float* rob = (const float*)d_in[15];
    float* out = (float*)d_out;

    char* p = (char*)d_ws;
    float* hb0          = (float*)p;                        // 262144 B
    float* hb1          = (float*)(p + 262144);             // 262144 B
    unsigned short* w1h = (unsigned short*)(p + 524288);    // 131072 B
    unsigned short* w1l = (unsigned short*)(p + 655360);    // 131072 B
    unsigned short* w2h = (unsigned short*)(p + 786432);    // 131072 B
    unsigned short* w2l = (unsigned short*)(p + 917504);    // 131072 B
    unsigned short* w3h = (unsigned short*)(p + 1048576);   // 4718592 B
    unsigned short* w3l = (unsigned short*)(p + 5767168);   // 4718592 B

    prep_kernel<<<dim3(256), dim3(256), 0, stream>>>(
        x0, iW1, ib1, iW2, ib2, iW3, ib3, vW1, vW2, vW3,
        hb0, w1h, w1l, w2h, w2l, w3h, w3l);

    float* hb[2] = {hb0, hb1};
    for (int t = 0; t < Tt; ++t) {
        step_kernel<<<dim3(256), dim3(256), 0, stream>>>(
            hb[t & 1], hb[(t + 1) & 1], logsigs, vb1, vb2, vb3, roW, rob,
            w1h, w1l, w2h, w2l, w3h, w3l, out, t);
    }
    // after t=511 the final h sits in hb[0] (512 is even)
    readout_last<<<dim3(8), dim3(256), 0, stream>>>(hb0, roW, rob, out);
}